// Round 10
// baseline (657.173 us; speedup 1.0000x reference)
//
#include <hip/hip_runtime.h>

typedef __attribute__((ext_vector_type(8))) short short8;
typedef __attribute__((ext_vector_type(4))) float f32x4;

// async global->LDS, 16B per lane. LDS dest = wave-uniform base (+ lane*16 by HW).
#define GLL16(gp, lp) __builtin_amdgcn_global_load_lds( \
    (__attribute__((address_space(1))) void*)(gp), \
    (__attribute__((address_space(3))) void*)(lp), 16, 0, 0)

__device__ __forceinline__ unsigned short f2b(float f) {
  unsigned int u = __builtin_bit_cast(unsigned int, f);
  u += 0x7fffu + ((u >> 16) & 1u);   // RNE; inputs are finite
  return (unsigned short)(u >> 16);
}
__device__ __forceinline__ float b2f(unsigned short s) {
  unsigned int u = ((unsigned int)s) << 16;
  return __builtin_bit_cast(float, u);
}

// ---------------- f32 -> bf16 straight convert (Xd, Xo) ----------------
__global__ __launch_bounds__(256) void conv_k(const float* __restrict__ in,
                                              short8* __restrict__ out, long n8) {
  for (long i = (long)blockIdx.x * 256 + threadIdx.x; i < n8;
       i += (long)gridDim.x * 256) {
    const float4* p = (const float4*)in + 2 * i;
    float4 a = p[0], b = p[1];
    short8 v;
    v[0] = (short)f2b(a.x); v[1] = (short)f2b(a.y);
    v[2] = (short)f2b(a.z); v[3] = (short)f2b(a.w);
    v[4] = (short)f2b(b.x); v[5] = (short)f2b(b.y);
    v[6] = (short)f2b(b.z); v[7] = (short)f2b(b.w);
    out[i] = v;
  }
}

// ------------- transpose+convert weights: in (K x C f32) -> out (C x K bf16) -------------
// inter=1 (Wv): output row for input col c = 4*(c&1023) + (c>>10)  (p = 4d+h head-interleave)
__global__ __launch_bounds__(256) void tconv_k(const float* __restrict__ in,
                                               unsigned short* __restrict__ out,
                                               int K, int C, int inter) {
  __shared__ float t[32][33];
  int k0 = blockIdx.x * 32, c0 = blockIdx.y * 32;
  int tx = threadIdx.x & 31, ty = threadIdx.x >> 5;
#pragma unroll
  for (int p = 0; p < 4; ++p)
    t[ty + p * 8][tx] = in[(size_t)(k0 + ty + p * 8) * C + c0 + tx];
  __syncthreads();
#pragma unroll
  for (int p = 0; p < 4; ++p) {
    int c = ty + p * 8;
    int gc = c0 + c;
    int orow = inter ? ((gc & 1023) * 4 + (gc >> 10)) : gc;
    out[(size_t)orow * K + k0 + tx] = f2b(t[tx][c]);
  }
}

// ======== PERSISTENT V-GEMM: 256x128 tiles, BK=32, stream PM mtiles per block ========
// Grid = 256 blocks (1/CU): block owns one 128-col B-panel, streams PM mtiles x 32
// K-tiles as ONE composite pipeline (triple-buffer ring, counted vmcnt(3), 1 raw
// barrier/tile). Per-mtile epilogue uses raw barriers + lgkmcnt ONLY (no vmcnt drain)
// so next-mtile stages stay in flight. Zs has a dedicated 32KB region (ring untouched).
// Scores read per-thread direct from global (h = l&3 identity, 64B-coalesced).
// LDS packing (R4/R9-verified): 2 rows per 128B super-row, chunk=(par<<2|kc)^(sr&7).
template <int KD>
__global__ __launch_bounds__(512, 2) void gemm_vper(
    const unsigned short* __restrict__ A, const unsigned short* __restrict__ Bt,
    const float* __restrict__ bias, const float* __restrict__ sc,
    float* __restrict__ Z, int PM) {
  __shared__ __align__(16) char ring[73728];   // 3 bufs x (A 16KB + B 8KB)
  __shared__ __align__(16) float Zs[256 * 32]; // 32KB, separate from ring

  constexpr int NKT = KD / 32;                 // 32
  constexpr long PANEL = 256L * KD * 2;        // A-panel bytes per mtile
  int tid = threadIdx.x;
  int bid = blockIdx.x;
  int cpx = gridDim.x >> 3;                    // 256 blocks: bijective XCD swizzle
  int lb = (bid & 7) * cpx + (bid >> 3);
  int nt0 = lb >> 3;                           // 32 ntiles (XCD chunk = 4 ntiles)
  int mg = lb & 7;                             // 8 mgroups x PM mtiles
  long mrow0 = (long)mg * PM * 256;            // first row of this block's stream
  int l = tid & 63, wid = tid >> 6, wm = wid >> 1, wn = wid & 1;

  // staging source mapping (inverse of read swizzle), R4/R9-verified
  int srg = tid >> 3, slot = tid & 7;
  int se = slot ^ (srg & 7);
  int par = se >> 2, kc = se & 3;
  int rowb = srg * 2 + par;
  const char* aT = (const char*)(A + mrow0 * KD) + (long)rowb * (KD * 2) + kc * 16;
  const char* bT = (const char*)(Bt + (long)nt0 * 128 * KD) + (long)rowb * (KD * 2) + kc * 16;
  char* ldsb = (char*)ring;
  int dstOff = wid * 1024;

  const int TOT = PM * NKT;                    // composite tiles
  auto stage = [&](int g) {                    // 3 x GLL16 (A 16KB, B 8KB)
    long ko = (long)(g >> 5) * PANEL + (g & 31) * 64;
    int bb = (g % 3) * 24576;
    GLL16(aT + ko,                  ldsb + bb + dstOff);
    GLL16(aT + 128 * (KD * 2) + ko, ldsb + bb + 8192 + dstOff);
    GLL16(bT + (g & 31) * 64,       ldsb + bb + 16384 + dstOff);
  };

  // read offsets (swizzled), R9-verified
  int ar = l & 15, kcl = l >> 4;
  int aoffR[4], boffR[4];
#pragma unroll
  for (int m = 0; m < 4; ++m) {
    int wr = wm * 64 + m * 16 + ar, sr = wr >> 1;
    aoffR[m] = sr * 128 + (((((wr & 1) << 2) | kcl) ^ (sr & 7)) << 4);
  }
#pragma unroll
  for (int n = 0; n < 4; ++n) {
    int br = wn * 64 + n * 16 + ar, sr = br >> 1;
    boffR[n] = 16384 + sr * 128 + (((((br & 1) << 2) | kcl) ^ (sr & 7)) << 4);
  }

  f32x4 zero = {0.f, 0.f, 0.f, 0.f};
  f32x4 acc[4][4];
#pragma unroll
  for (int m = 0; m < 4; ++m)
#pragma unroll
    for (int n = 0; n < 4; ++n) acc[m][n] = zero;

  stage(0);
  stage(1);                                    // 2-tile prefetch window

  for (int g = 0; g < TOT; ++g) {
    if (g + 1 < TOT) asm volatile("s_waitcnt vmcnt(3)" ::: "memory");
    else             asm volatile("s_waitcnt vmcnt(0)" ::: "memory");
    __builtin_amdgcn_s_barrier();
    asm volatile("" ::: "memory");
    if (g + 2 < TOT) stage(g + 2);

    const char* base = ldsb + (g % 3) * 24576;
    short8 af[4], bf[4];
#pragma unroll
    for (int m = 0; m < 4; ++m) af[m] = *(const short8*)(base + aoffR[m]);
#pragma unroll
    for (int n = 0; n < 4; ++n) bf[n] = *(const short8*)(base + boffR[n]);
#pragma unroll
    for (int m = 0; m < 4; ++m)
#pragma unroll
      for (int n = 0; n < 4; ++n)
        acc[m][n] = __builtin_amdgcn_mfma_f32_16x16x32_bf16(af[m], bf[n],
                                                            acc[m][n], 0, 0, 0);

    if ((g & 31) == 31) {
      // ---------- per-mtile epilogue (raw barriers; ring stages stay in flight) ----------
      long m0 = mrow0 + (long)(g >> 5) * 256;
      // per-thread scores: h = l&3; rows = wm*64 + m*16 + (l>>4)*4 + r  (64B-coalesced)
      float scv[4][4];
#pragma unroll
      for (int m = 0; m < 4; ++m)
#pragma unroll
        for (int r = 0; r < 4; ++r)
          scv[m][r] = sc[(m0 + wm * 64 + m * 16 + ((l >> 4) << 2) + r) * 4 + (l & 3)];
#pragma unroll
      for (int n = 0; n < 4; ++n) {
        int pl = wn * 64 + n * 16 + (l & 15);  // local permuted col, p = 4d+h
        int pg = nt0 * 128 + pl;
        float bb = bias[(pg & 3) * 1024 + (pg >> 2)];
#pragma unroll
        for (int m = 0; m < 4; ++m) {
          int rl = wm * 64 + m * 16 + ((l >> 4) << 2);
#pragma unroll
          for (int r = 0; r < 4; ++r) {
            float z = scv[m][r] * (acc[m][n][r] + bb);
            z = fmaxf(z, __shfl_xor(z, 1));    // max over heads (adjacent p)
            z = fmaxf(z, __shfl_xor(z, 2));
            if ((l & 3) == 0) Zs[(rl + r) * 32 + (pl >> 2)] = z;
          }
        }
      }
      asm volatile("s_waitcnt lgkmcnt(0)" ::: "memory");
      __builtin_amdgcn_s_barrier();
      asm volatile("" ::: "memory");
#pragma unroll
      for (int it = 0; it < 4; ++it) {         // coalesced float4 stores, 256x32 f32
        int i = it * 512 + tid;
        int row = i >> 3, q = i & 7;
        f32x4 v = *(const f32x4*)&Zs[row * 32 + q * 4];
        *(f32x4*)&Z[(m0 + row) * 1024 + nt0 * 32 + q * 4] = v;
      }
      // Zs not reused until next epilogue (32 tiles of barriers away) -> no 2nd barrier
#pragma unroll
      for (int m = 0; m < 4; ++m)
#pragma unroll
        for (int n = 0; n < 4; ++n) acc[m][n] = zero;
    }
  }
}

// ======== 256x256 BK=64 quadrant-phase GEMM (R7) — Q and K GEMMs ========
template <int KD, int NTI, int EPI>
__global__ __launch_bounds__(512, 2) void gemm_p(
    const unsigned short* __restrict__ A, const unsigned short* __restrict__ Bt,
    const float* __restrict__ bias, const unsigned short* __restrict__ Qb,
    unsigned short* __restrict__ outb, float* __restrict__ sc) {
  __shared__ __align__(16) char lds[131072];   // A slots 0..3 x16KB, B at +64KB

  constexpr int NKT = KD / 64;
  int tid = threadIdx.x;
  int bid = blockIdx.x;
  int cpx = gridDim.x >> 3;
  int lb = (bid & 7) * cpx + (bid >> 3);
  int mtile = lb / NTI, nt0 = lb % NTI;
  long m0 = (long)mtile * 256;
  int l = tid & 63, wid = tid >> 6, wm = wid >> 2, wn = wid & 3;

  int rowg = tid >> 3;
  int swz = (tid & 7) ^ (rowg & 7);
  const char* aSrc = (const char*)(A + m0 * KD) + (long)rowg * (KD * 2) + swz * 16;
  const char* bSrc = (const char*)(Bt + (long)nt0 * 256 * KD) + (long)rowg * (KD * 2) + swz * 16;
  char* ldsb = (char*)lds;
  int dstOff = wid * 1024;

  auto stageA = [&](int hh, int tt) {
    char* base = ldsb + ((tt & 1) * 32768 + hh * 16384) + dstOff;
    const char* s = aSrc + (long)(hh * 128) * (KD * 2) + tt * 128;
    GLL16(s, base);
    GLL16(s + (long)64 * (KD * 2), base + 8192);
  };
  auto stageB = [&](int hh, int tt) {
    char* base = ldsb + 65536 + ((tt & 1) * 32768 + hh * 16384) + dstOff;
    const char* s = bSrc + (long)(hh * 128) * (KD * 2) + tt * 128;
    GLL16(s, base);
    GLL16(s + (long)64 * (KD * 2), base + 8192);
  };

  int ar = l & 15, kcl = l >> 4;
  int x0 = ((kcl ^ (ar & 7)) << 4);
  int x1 = (((4 | kcl) ^ (ar & 7)) << 4);
  int thrA = (wm * 64 + ar) * 128;
  int thrB = (wn * 32 + ar) * 128;

  short8 aA[4][2], aB[4][2], b0[2][2], b1[2][2];

#define RD_A(dst, slotoff)                                                  \
  do {                                                                      \
    const char* p_ = ldsb + (slotoff) + thrA;                               \
    _Pragma("unroll") for (int m_ = 0; m_ < 4; ++m_) {                      \
      dst[m_][0] = *(const short8*)(p_ + x0 + m_ * 2048);                   \
      dst[m_][1] = *(const short8*)(p_ + x1 + m_ * 2048);                   \
    }                                                                       \
  } while (0)
#define RD_B(dst, slotoff)                                                  \
  do {                                                                      \
    const char* p_ = ldsb + 65536 + (slotoff) + thrB;                       \
    _Pragma("unroll") for (int n_ = 0; n_ < 2; ++n_) {                      \
      dst[n_][0] = *(const short8*)(p_ + x0 + n_ * 2048);                   \
      dst[n_][1] = *(const short8*)(p_ + x1 + n_ * 2048);                   \
    }                                                                       \
  } while (0)
#define MFQ(q, am, bn)                                                      \
  do {                                                                      \
    __builtin_amdgcn_s_setprio(1);                                          \
    _Pragma("unroll") for (int m_ = 0; m_ < 4; ++m_)                        \
        _Pragma("unroll") for (int n_ = 0; n_ < 2; ++n_)                    \
            _Pragma("unroll") for (int k_ = 0; k_ < 2; ++k_)                \
                acc[q][m_ * 2 + n_] = __builtin_amdgcn_mfma_f32_16x16x32_bf16( \
                    am[m_][k_], bn[n_][k_], acc[q][m_ * 2 + n_], 0, 0, 0);  \
    __builtin_amdgcn_s_setprio(0);                                          \
  } while (0)
#define VM(n) asm volatile("s_waitcnt vmcnt(" #n ")" ::: "memory")
#define BAR() __builtin_amdgcn_s_barrier()
#define CLOB() asm volatile("" ::: "memory")

  f32x4 zero = {0.f, 0.f, 0.f, 0.f};
  f32x4 acc[4][8];
#pragma unroll
  for (int q = 0; q < 4; ++q)
#pragma unroll
    for (int f = 0; f < 8; ++f) acc[q][f] = zero;

  stageA(0, 0); stageB(0, 0); stageB(1, 0); stageA(1, 0);
  VM(4); BAR(); CLOB();
  RD_A(aA, 0);
  RD_B(b0, 0);

  for (int t = 0; t < NKT - 1; ++t) {
    int aS = (t & 1) * 32768;
    int bS = aS;
    int aS2 = aS ^ 32768;
    stageA(0, t + 1);
    VM(4); BAR(); CLOB();
    RD_B(b1, bS + 16384);
    MFQ(0, aA, b0);
    stageB(0, t + 1);
    VM(4); BAR(); CLOB();
    RD_A(aB, aS + 16384);
    MFQ(1, aA, b1);
    stageB(1, t + 1);
    VM(4); BAR(); CLOB();
    RD_A(aA, aS2);
    MFQ(2, aB, b0);
    stageA(1, t + 1);
    VM(4); BAR(); CLOB();
    RD_B(b0, aS2);
    MFQ(3, aB, b1);
  }
  {
    constexpr int t = NKT - 1;
    int aS = (t & 1) * 32768;
    VM(2); BAR(); CLOB();
    RD_B(b1, aS + 16384);
    MFQ(0, aA, b0);
    VM(0); BAR(); CLOB();
    RD_A(aB, aS + 16384);
    MFQ(1, aA, b1);
    MFQ(2, aB, b0);
    MFQ(3, aB, b1);
  }
#undef RD_A
#undef RD_B
#undef MFQ
#undef VM
#undef BAR
#undef CLOB

  if constexpr (EPI == 0) {
#pragma unroll
    for (int qm = 0; qm < 2; ++qm)
#pragma unroll
      for (int qn = 0; qn < 2; ++qn) {
        int q = qm * 2 + qn;
#pragma unroll
        for (int n = 0; n < 2; ++n) {
          int col = nt0 * 256 + qn * 128 + wn * 32 + n * 16 + (l & 15);
          float bb = bias[col];
#pragma unroll
          for (int m = 0; m < 4; ++m) {
            long rowb = m0 + qm * 128 + wm * 64 + m * 16 + ((l >> 4) << 2);
#pragma unroll
            for (int r = 0; r < 4; ++r)
              outb[(rowb + r) * 512 + col] = f2b(acc[q][m * 2 + n][r] + bb);
          }
        }
      }
  } else {
    float part[2][2][4][4];
#pragma unroll
    for (int qm = 0; qm < 2; ++qm)
#pragma unroll
      for (int qn = 0; qn < 2; ++qn)
#pragma unroll
        for (int m = 0; m < 4; ++m)
#pragma unroll
          for (int r = 0; r < 4; ++r) part[qm][qn][m][r] = 0.f;
#pragma unroll
    for (int qm = 0; qm < 2; ++qm)
#pragma unroll
      for (int qn = 0; qn < 2; ++qn) {
        int q = qm * 2 + qn;
#pragma unroll
        for (int n = 0; n < 2; ++n) {
          int col = nt0 * 256 + qn * 128 + wn * 32 + n * 16 + (l & 15);
          float bb = bias[col];
#pragma unroll
          for (int m = 0; m < 4; ++m) {
            long rowb = m0 + qm * 128 + wm * 64 + m * 16 + ((l >> 4) << 2);
#pragma unroll
            for (int r = 0; r < 4; ++r) {
              float kv = acc[q][m * 2 + n][r] + bb;
              part[qm][qn][m][r] += kv * b2f(Qb[(rowb + r) * 512 + col]);
            }
          }
        }
      }
    __syncthreads();
    float (*sred)[2][4] = (float(*)[2][4])ldsb;   // [256][head2][wn4]
#pragma unroll
    for (int qm = 0; qm < 2; ++qm)
#pragma unroll
      for (int qn = 0; qn < 2; ++qn)
#pragma unroll
        for (int m = 0; m < 4; ++m)
#pragma unroll
          for (int r = 0; r < 4; ++r) {
            float s = part[qm][qn][m][r];
            s += __shfl_xor(s, 1);
            s += __shfl_xor(s, 2);
            s += __shfl_xor(s, 4);
            s += __shfl_xor(s, 8);
            if ((l & 15) == 0)
              sred[qm * 128 + wm * 64 + m * 16 + ((l >> 4) << 2) + r][qn][wn] = s;
          }
    __syncthreads();
    {
      int row = tid >> 1, hh = tid & 1;
      float v = sred[row][hh][0] + sred[row][hh][1] + sred[row][hh][2] +
                sred[row][hh][3];
      sc[(m0 + row) * 4 + nt0 * 2 + hh] = v;
    }
  }
}

// ---------------- fallback (only if ws too small): fp32, correct but slow ----------------
__global__ __launch_bounds__(256) void naive_k(
    const float* __restrict__ Xd, const float* __restrict__ Xo,
    const float* __restrict__ Wq, const float* __restrict__ bq,
    const float* __restrict__ Wk, const float* __restrict__ bk,
    const float* __restrict__ Wv, const float* __restrict__ bv,
    float* __restrict__ Z) {
  int i = blockIdx.x, t = threadIdx.x;
  __shared__ float xd[1024], xo[512], s[4];
  for (int j = t; j < 1024; j += 256) xd[j] = Xd[(size_t)i * 1024 + j];
  for (int j = t; j < 512; j += 256) xo[j] = Xo[(size_t)i * 512 + j];
  if (t < 4) s[t] = 0.f;
  __syncthreads();
  for (int c = t; c < 512; c += 256) {
    float q = bq[c], k = bk[c];
    for (int j = 0; j < 512; ++j) q += xo[j] * Wq[(size_t)j * 512 + c];
    for (int j = 0; j < 1024; ++j) k += xd[j] * Wk[(size_t)j * 512 + c];
    atomicAdd(&s[c >> 7], q * k);
  }
  __syncthreads();
  for (int d = t; d < 1024; d += 256) {
    float z = -INFINITY;
    for (int h = 0; h < 4; ++h) {
      float v = bv[h * 1024 + d];
      for (int j = 0; j < 1024; ++j) v += xd[j] * Wv[(size_t)j * 4096 + h * 1024 + d];
      z = fmaxf(z, s[h] * v);
    }
    Z[(size_t)i * 1024 + d] = z;
  }
}

extern "C" void kernel_launch(void* const* d_in, const int* in_sizes, int n_in,
                              void* d_out, int out_size, void* d_ws, size_t ws_size,
                              hipStream_t stream) {
  const float* Xd = (const float*)d_in[0];
  const float* Xo = (const float*)d_in[1];
  const float* Wq = (const float*)d_in[2];
  const float* bq = (const float*)d_in[3];
  const float* Wk = (const float*)d_in[4];
  const float* bk = (const float*)d_in[5];
  const float* Wv = (const float*)d_in[6];
  const float* bv = (const float*)d_in[7];
  float* Z = (float*)d_out;
  long N = in_sizes[0] / 1024;

  size_t sz_Xd = (size_t)N * 1024 * 2, sz_Xo = (size_t)N * 512 * 2;
  size_t sz_Wq = (size_t)512 * 512 * 2, sz_Wk = (size_t)512 * 1024 * 2;
  size_t sz_Wv = (size_t)4096 * 1024 * 2;
  size_t sz_Qb = (size_t)N * 512 * 2, sz_sc = (size_t)N * 4 * 4;
  size_t o_Xo = sz_Xd, o_Wq = o_Xo + sz_Xo, o_Wk = o_Wq + sz_Wq,
         o_Wv = o_Wk + sz_Wk, o_Qb = o_Wv + sz_Wv, o_sc = o_Qb + sz_Qb;
  size_t need = o_sc + sz_sc;

  long mtiles = N / 256;
  if (ws_size < need || (N % 256) != 0 || (mtiles % 8) != 0) {
    naive_k<<<(int)N, 256, 0, stream>>>(Xd, Xo, Wq, bq, Wk, bk, Wv, bv, Z);
    return;
  }

  char* w = (char*)d_ws;
  unsigned short* Xd_b = (unsigned short*)w;
  unsigned short* Xo_b = (unsigned short*)(w + o_Xo);
  unsigned short* Wq_t = (unsigned short*)(w + o_Wq);
  unsigned short* Wk_t = (unsigned short*)(w + o_Wk);
  unsigned short* Wv_p = (unsigned short*)(w + o_Wv);
  unsigned short* Qb   = (unsigned short*)(w + o_Qb);
  float* sc = (float*)(w + o_sc);

  conv_k<<<2048, 256, 0, stream>>>(Xd, (short8*)Xd_b, N * 1024 / 8);
  conv_k<<<2048, 256, 0, stream>>>(Xo, (short8*)Xo_b, N * 512 / 8);
  tconv_k<<<dim3(16, 16), 256, 0, stream>>>(Wq, Wq_t, 512, 512, 0);
  tconv_k<<<dim3(32, 16), 256, 0, stream>>>(Wk, Wk_t, 1024, 512, 0);
  tconv_k<<<dim3(32, 128), 256, 0, stream>>>(Wv, Wv_p, 1024, 4096, 1);

  int mt = (int)mtiles;
  int PM = mt / 8;
  gemm_p<512, 2, 0><<<mt * 2, 512, 0, stream>>>(Xo_b, Wq_t, bq, nullptr, Qb,
                                                nullptr);
  gemm_p<1024, 2, 1><<<mt * 2, 512, 0, stream>>>(Xd_b, Wk_t, bk, Qb, nullptr,
                                                 sc);
  gemm_vper<1024><<<256, 512, 0, stream>>>(Xd_b, Wv_p, bv, sc, Z, PM);
}

// Round 11
// 493.027 us; speedup vs baseline: 1.3329x; 1.3329x over previous
//
#include <hip/hip_runtime.h>

typedef __attribute__((ext_vector_type(8))) short short8;
typedef __attribute__((ext_vector_type(4))) float f32x4;
typedef __attribute__((ext_vector_type(16))) float f32x16;

// async global->LDS, 16B per lane. LDS dest = wave-uniform base (+ lane*16 by HW).
#define GLL16(gp, lp) __builtin_amdgcn_global_load_lds( \
    (__attribute__((address_space(1))) void*)(gp), \
    (__attribute__((address_space(3))) void*)(lp), 16, 0, 0)

__device__ __forceinline__ unsigned short f2b(float f) {
  unsigned int u = __builtin_bit_cast(unsigned int, f);
  u += 0x7fffu + ((u >> 16) & 1u);   // RNE; inputs are finite
  return (unsigned short)(u >> 16);
}
__device__ __forceinline__ float b2f(unsigned short s) {
  unsigned int u = ((unsigned int)s) << 16;
  return __builtin_bit_cast(float, u);
}

// ---------------- f32 -> bf16 straight convert (Xd, Xo) ----------------
__global__ __launch_bounds__(256) void conv_k(const float* __restrict__ in,
                                              short8* __restrict__ out, long n8) {
  for (long i = (long)blockIdx.x * 256 + threadIdx.x; i < n8;
       i += (long)gridDim.x * 256) {
    const float4* p = (const float4*)in + 2 * i;
    float4 a = p[0], b = p[1];
    short8 v;
    v[0] = (short)f2b(a.x); v[1] = (short)f2b(a.y);
    v[2] = (short)f2b(a.z); v[3] = (short)f2b(a.w);
    v[4] = (short)f2b(b.x); v[5] = (short)f2b(b.y);
    v[6] = (short)f2b(b.z); v[7] = (short)f2b(b.w);
    out[i] = v;
  }
}

// ------------- transpose+convert weights: in (K x C f32) -> out (C x K bf16) -------------
// inter=1 (Wv): output row for input col c = 4*(c&1023) + (c>>10)  (p = 4d+h head-interleave)
__global__ __launch_bounds__(256) void tconv_k(const float* __restrict__ in,
                                               unsigned short* __restrict__ out,
                                               int K, int C, int inter) {
  __shared__ float t[32][33];
  int k0 = blockIdx.x * 32, c0 = blockIdx.y * 32;
  int tx = threadIdx.x & 31, ty = threadIdx.x >> 5;
#pragma unroll
  for (int p = 0; p < 4; ++p)
    t[ty + p * 8][tx] = in[(size_t)(k0 + ty + p * 8) * C + c0 + tx];
  __syncthreads();
#pragma unroll
  for (int p = 0; p < 4; ++p) {
    int c = ty + p * 8;
    int gc = c0 + c;
    int orow = inter ? ((gc & 1023) * 4 + (gc >> 10)) : gc;
    out[(size_t)orow * K + k0 + tx] = f2b(t[tx][c]);
  }
}

// ======== V-GEMM v3: R9 engine (256x128, BK=32, triple-ring, vmcnt(3), 2 blk/CU)
// ======== with 32x32x16 MFMA (m119: 32x32 pipe 2495 vs 2176 TF for 16x16).
// LDS content/staging identical to R9 (verified); only read addressing + epilogue
// indexing change. A/B frag: lane l -> row/col (l&31), k chunk kc = 2*ks + (l>>5).
// C/D (verified m74/m101): col = l&31, row = (r&3) + 8*(r>>2) + 4*(l>>5).
template <int KD>
__global__ __launch_bounds__(512, 4) void gemm_v32(
    const unsigned short* __restrict__ A, const unsigned short* __restrict__ Bt,
    const float* __restrict__ bias, const float* __restrict__ sc,
    float* __restrict__ Z) {
  __shared__ __align__(16) char lds[73728];    // 3 bufs x (A 16KB + B 8KB)
  __shared__ float s_sc[1024];

  constexpr int NKT = KD / 32;
  int tid = threadIdx.x;
  int bid = blockIdx.x;
  int cpx = gridDim.x >> 3;                    // grid % 8 == 0 (bijective XCD swizzle)
  int lb = (bid & 7) * cpx + (bid >> 3);
  int mtile = lb >> 5, nt0 = lb & 31;          // 32 ntiles of 128 cols
  long m0 = (long)mtile * 256;
  int l = tid & 63, wid = tid >> 6, wm = wid >> 1, wn = wid & 1;

  // staging source mapping (inverse of read swizzle), R4/R9-verified:
  // LDS[sr][slot] holds A[row=2sr+par][16B chunk kc], (par<<2|kc) = slot^(sr&7).
  int srg = tid >> 3, slot = tid & 7;
  int se = slot ^ (srg & 7);
  int par = se >> 2, kc = se & 3;
  int rowb = srg * 2 + par;
  const char* aT = (const char*)(A + m0 * KD) + (long)rowb * (KD * 2) + kc * 16;
  const char* bT = (const char*)(Bt + (long)nt0 * 128 * KD) + (long)rowb * (KD * 2) + kc * 16;
  char* ldsb = (char*)lds;
  int dstOff = wid * 1024;

  auto stage = [&](int kt, int bb) {           // one K-tile: A 16KB (2x) + B 8KB (1x)
    int ko = kt * 64;
    GLL16(aT + ko,                  ldsb + bb * 24576 + dstOff);
    GLL16(aT + 128 * (KD * 2) + ko, ldsb + bb * 24576 + 8192 + dstOff);
    GLL16(bT + ko,                  ldsb + bb * 24576 + 16384 + dstOff);
  };

  for (int i = tid; i < 1024; i += 512) s_sc[i] = sc[m0 * 4 + i];

  // read offsets for 32x32x16 frags (within buffer), swizzled pack-inverse
  int aoffR[2][2], boffR[2][2];
#pragma unroll
  for (int mb = 0; mb < 2; ++mb)
#pragma unroll
    for (int ks = 0; ks < 2; ++ks) {
      int row = wm * 64 + mb * 32 + (l & 31);
      int kcd = 2 * ks + (l >> 5);
      int sr = row >> 1;
      aoffR[mb][ks] = sr * 128 + (((((row & 1) << 2) | kcd) ^ (sr & 7)) << 4);
    }
#pragma unroll
  for (int nb = 0; nb < 2; ++nb)
#pragma unroll
    for (int ks = 0; ks < 2; ++ks) {
      int col = wn * 64 + nb * 32 + (l & 31);
      int kcd = 2 * ks + (l >> 5);
      int sr = col >> 1;
      boffR[nb][ks] = 16384 + sr * 128 + (((((col & 1) << 2) | kcd) ^ (sr & 7)) << 4);
    }

  f32x16 acc[2][2];
#pragma unroll
  for (int mb = 0; mb < 2; ++mb)
#pragma unroll
    for (int nb = 0; nb < 2; ++nb)
#pragma unroll
      for (int r = 0; r < 16; ++r) acc[mb][nb][r] = 0.f;

  stage(0, 0);
  stage(1, 1);                                 // 2-tile prefetch window

  for (int t = 0; t < NKT; ++t) {
    if (t + 1 < NKT) asm volatile("s_waitcnt vmcnt(3)" ::: "memory");
    else             asm volatile("s_waitcnt vmcnt(0)" ::: "memory");
    __builtin_amdgcn_s_barrier();
    asm volatile("" ::: "memory");
    if (t + 2 < NKT) stage(t + 2, (t + 2) % 3);

    const char* base = ldsb + (t % 3) * 24576;
    short8 af[2][2], bf[2][2];
#pragma unroll
    for (int mb = 0; mb < 2; ++mb)
#pragma unroll
      for (int ks = 0; ks < 2; ++ks)
        af[mb][ks] = *(const short8*)(base + aoffR[mb][ks]);
#pragma unroll
    for (int nb = 0; nb < 2; ++nb)
#pragma unroll
      for (int ks = 0; ks < 2; ++ks)
        bf[nb][ks] = *(const short8*)(base + boffR[nb][ks]);
#pragma unroll
    for (int ks = 0; ks < 2; ++ks)
#pragma unroll
      for (int mb = 0; mb < 2; ++mb)
#pragma unroll
        for (int nb = 0; nb < 2; ++nb)
          acc[mb][nb] = __builtin_amdgcn_mfma_f32_32x32x16_bf16(
              af[mb][ks], bf[nb][ks], acc[mb][nb], 0, 0, 0);
  }

  // ---------------- fused epilogue: scale by scores, max over heads ----------------
  __syncthreads();                             // drain before LDS reuse
  float* Zs = (float*)ldsb;                    // 256 x 32 f32 = 32 KB
  int hi = l >> 5, h = l & 3;
#pragma unroll
  for (int mb = 0; mb < 2; ++mb)
#pragma unroll
    for (int nb = 0; nb < 2; ++nb) {
      int pl = wn * 64 + nb * 32 + (l & 31);   // local permuted col, p = 4d+h
      int pg = nt0 * 128 + pl;
      float bb = bias[(pg & 3) * 1024 + (pg >> 2)];
#pragma unroll
      for (int r = 0; r < 16; ++r) {
        int row = wm * 64 + mb * 32 + (r & 3) + 8 * (r >> 2) + 4 * hi;
        float z = s_sc[row * 4 + h] * (acc[mb][nb][r] + bb);
        z = fmaxf(z, __shfl_xor(z, 1));        // max over heads (adjacent p)
        z = fmaxf(z, __shfl_xor(z, 2));
        if (h == 0) Zs[row * 32 + (pl >> 2)] = z;
      }
    }
  __syncthreads();
#pragma unroll
  for (int it = 0; it < 4; ++it) {             // coalesced float4 stores, 256x32 f32
    int i = it * 512 + tid;
    int row = i >> 3, q = i & 7;
    f32x4 v = *(const f32x4*)&Zs[row * 32 + q * 4];
    *(f32x4*)&Z[(m0 + row) * 1024 + nt0 * 32 + q * 4] = v;
  }
}

// ======== 256x256 BK=64 quadrant-phase GEMM (R7) — Q and K GEMMs ========
template <int KD, int NTI, int EPI>
__global__ __launch_bounds__(512, 2) void gemm_p(
    const unsigned short* __restrict__ A, const unsigned short* __restrict__ Bt,
    const float* __restrict__ bias, const unsigned short* __restrict__ Qb,
    unsigned short* __restrict__ outb, float* __restrict__ sc) {
  __shared__ __align__(16) char lds[131072];   // A slots 0..3 x16KB, B at +64KB

  constexpr int NKT = KD / 64;
  int tid = threadIdx.x;
  int bid = blockIdx.x;
  int cpx = gridDim.x >> 3;
  int lb = (bid & 7) * cpx + (bid >> 3);
  int mtile = lb / NTI, nt0 = lb % NTI;
  long m0 = (long)mtile * 256;
  int l = tid & 63, wid = tid >> 6, wm = wid >> 2, wn = wid & 3;

  int rowg = tid >> 3;
  int swz = (tid & 7) ^ (rowg & 7);
  const char* aSrc = (const char*)(A + m0 * KD) + (long)rowg * (KD * 2) + swz * 16;
  const char* bSrc = (const char*)(Bt + (long)nt0 * 256 * KD) + (long)rowg * (KD * 2) + swz * 16;
  char* ldsb = (char*)lds;
  int dstOff = wid * 1024;

  auto stageA = [&](int hh, int tt) {
    char* base = ldsb + ((tt & 1) * 32768 + hh * 16384) + dstOff;
    const char* s = aSrc + (long)(hh * 128) * (KD * 2) + tt * 128;
    GLL16(s, base);
    GLL16(s + (long)64 * (KD * 2), base + 8192);
  };
  auto stageB = [&](int hh, int tt) {
    char* base = ldsb + 65536 + ((tt & 1) * 32768 + hh * 16384) + dstOff;
    const char* s = bSrc + (long)(hh * 128) * (KD * 2) + tt * 128;
    GLL16(s, base);
    GLL16(s + (long)64 * (KD * 2), base + 8192);
  };

  int ar = l & 15, kcl = l >> 4;
  int x0 = ((kcl ^ (ar & 7)) << 4);
  int x1 = (((4 | kcl) ^ (ar & 7)) << 4);
  int thrA = (wm * 64 + ar) * 128;
  int thrB = (wn * 32 + ar) * 128;

  short8 aA[4][2], aB[4][2], b0[2][2], b1[2][2];

#define RD_A(dst, slotoff)                                                  \
  do {                                                                      \
    const char* p_ = ldsb + (slotoff) + thrA;                               \
    _Pragma("unroll") for (int m_ = 0; m_ < 4; ++m_) {                      \
      dst[m_][0] = *(const short8*)(p_ + x0 + m_ * 2048);                   \
      dst[m_][1] = *(const short8*)(p_ + x1 + m_ * 2048);                   \
    }                                                                       \
  } while (0)
#define RD_B(dst, slotoff)                                                  \
  do {                                                                      \
    const char* p_ = ldsb + 65536 + (slotoff) + thrB;                       \
    _Pragma("unroll") for (int n_ = 0; n_ < 2; ++n_) {                      \
      dst[n_][0] = *(const short8*)(p_ + x0 + n_ * 2048);                   \
      dst[n_][1] = *(const short8*)(p_ + x1 + n_ * 2048);                   \
    }                                                                       \
  } while (0)
#define MFQ(q, am, bn)                                                      \
  do {                                                                      \
    __builtin_amdgcn_s_setprio(1);                                          \
    _Pragma("unroll") for (int m_ = 0; m_ < 4; ++m_)                        \
        _Pragma("unroll") for (int n_ = 0; n_ < 2; ++n_)                    \
            _Pragma("unroll") for (int k_ = 0; k_ < 2; ++k_)                \
                acc[q][m_ * 2 + n_] = __builtin_amdgcn_mfma_f32_16x16x32_bf16( \
                    am[m_][k_], bn[n_][k_], acc[q][m_ * 2 + n_], 0, 0, 0);  \
    __builtin_amdgcn_s_setprio(0);                                          \
  } while (0)
#define VM(n) asm volatile("s_waitcnt vmcnt(" #n ")" ::: "memory")
#define BAR() __builtin_amdgcn_s_barrier()
#define CLOB() asm volatile("" ::: "memory")

  f32x4 zero = {0.f, 0.f, 0.f, 0.f};
  f32x4 acc[4][8];
#pragma unroll
  for (int q = 0; q < 4; ++q)
#pragma unroll
    for (int f = 0; f < 8; ++f) acc[q][f] = zero;

  stageA(0, 0); stageB(0, 0); stageB(1, 0); stageA(1, 0);
  VM(4); BAR(); CLOB();
  RD_A(aA, 0);
  RD_B(b0, 0);

  for (int t = 0; t < NKT - 1; ++t) {
    int aS = (t & 1) * 32768;
    int bS = aS;
    int aS2 = aS ^ 32768;
    stageA(0, t + 1);
    VM(4); BAR(); CLOB();
    RD_B(b1, bS + 16384);
    MFQ(0, aA, b0);
    stageB(0, t + 1);
    VM(4); BAR(); CLOB();
    RD_A(aB, aS + 16384);
    MFQ(1, aA, b1);
    stageB(1, t + 1);
    VM(4); BAR(); CLOB();
    RD_A(aA, aS2);
    MFQ(2, aB, b0);
    stageA(1, t + 1);
    VM(4); BAR(); CLOB();
    RD_B(b0, aS2);
    MFQ(3, aB, b1);
  }
  {
    constexpr int t = NKT - 1;
    int aS = (t & 1) * 32768;
    VM(2); BAR(); CLOB();
    RD_B(b1, aS + 16384);
    MFQ(0, aA, b0);
    VM(0); BAR(); CLOB();
    RD_A(aB, aS + 16384);
    MFQ(1, aA, b1);
    MFQ(2, aB, b0);
    MFQ(3, aB, b1);
  }
#undef RD_A
#undef RD_B
#undef MFQ
#undef VM
#undef BAR
#undef CLOB

  if constexpr (EPI == 0) {
#pragma unroll
    for (int qm = 0; qm < 2; ++qm)
#pragma unroll
      for (int qn = 0; qn < 2; ++qn) {
        int q = qm * 2 + qn;
#pragma unroll
        for (int n = 0; n < 2; ++n) {
          int col = nt0 * 256 + qn * 128 + wn * 32 + n * 16 + (l & 15);
          float bb = bias[col];
#pragma unroll
          for (int m = 0; m < 4; ++m) {
            long rowb = m0 + qm * 128 + wm * 64 + m * 16 + ((l >> 4) << 2);
#pragma unroll
            for (int r = 0; r < 4; ++r)
              outb[(rowb + r) * 512 + col] = f2b(acc[q][m * 2 + n][r] + bb);
          }
        }
      }
  } else {
    float part[2][2][4][4];
#pragma unroll
    for (int qm = 0; qm < 2; ++qm)
#pragma unroll
      for (int qn = 0; qn < 2; ++qn)
#pragma unroll
        for (int m = 0; m < 4; ++m)
#pragma unroll
          for (int r = 0; r < 4; ++r) part[qm][qn][m][r] = 0.f;
#pragma unroll
    for (int qm = 0; qm < 2; ++qm)
#pragma unroll
      for (int qn = 0; qn < 2; ++qn) {
        int q = qm * 2 + qn;
#pragma unroll
        for (int n = 0; n < 2; ++n) {
          int col = nt0 * 256 + qn * 128 + wn * 32 + n * 16 + (l & 15);
          float bb = bias[col];
#pragma unroll
          for (int m = 0; m < 4; ++m) {
            long rowb = m0 + qm * 128 + wm * 64 + m * 16 + ((l >> 4) << 2);
#pragma unroll
            for (int r = 0; r < 4; ++r) {
              float kv = acc[q][m * 2 + n][r] + bb;
              part[qm][qn][m][r] += kv * b2f(Qb[(rowb + r) * 512 + col]);
            }
          }
        }
      }
    __syncthreads();
    float (*sred)[2][4] = (float(*)[2][4])ldsb;   // [256][head2][wn4]
#pragma unroll
    for (int qm = 0; qm < 2; ++qm)
#pragma unroll
      for (int qn = 0; qn < 2; ++qn)
#pragma unroll
        for (int m = 0; m < 4; ++m)
#pragma unroll
          for (int r = 0; r < 4; ++r) {
            float s = part[qm][qn][m][r];
            s += __shfl_xor(s, 1);
            s += __shfl_xor(s, 2);
            s += __shfl_xor(s, 4);
            s += __shfl_xor(s, 8);
            if ((l & 15) == 0)
              sred[qm * 128 + wm * 64 + m * 16 + ((l >> 4) << 2) + r][qn][wn] = s;
          }
    __syncthreads();
    {
      int row = tid >> 1, hh = tid & 1;
      float v = sred[row][hh][0] + sred[row][hh][1] + sred[row][hh][2] +
                sred[row][hh][3];
      sc[(m0 + row) * 4 + nt0 * 2 + hh] = v;
    }
  }
}

// ---------------- fallback (only if ws too small): fp32, correct but slow ----------------
__global__ __launch_bounds__(256) void naive_k(
    const float* __restrict__ Xd, const float* __restrict__ Xo,
    const float* __restrict__ Wq, const float* __restrict__ bq,
    const float* __restrict__ Wk, const float* __restrict__ bk,
    const float* __restrict__ Wv, const float* __restrict__ bv,
    float* __restrict__ Z) {
  int i = blockIdx.x, t = threadIdx.x;
  __shared__ float xd[1024], xo[512], s[4];
  for (int j = t; j < 1024; j += 256) xd[j] = Xd[(size_t)i * 1024 + j];
  for (int j = t; j < 512; j += 256) xo[j] = Xo[(size_t)i * 512 + j];
  if (t < 4) s[t] = 0.f;
  __syncthreads();
  for (int c = t; c < 512; c += 256) {
    float q = bq[c], k = bk[c];
    for (int j = 0; j < 512; ++j) q += xo[j] * Wq[(size_t)j * 512 + c];
    for (int j = 0; j < 1024; ++j) k += xd[j] * Wk[(size_t)j * 512 + c];
    atomicAdd(&s[c >> 7], q * k);
  }
  __syncthreads();
  for (int d = t; d < 1024; d += 256) {
    float z = -INFINITY;
    for (int h = 0; h < 4; ++h) {
      float v = bv[h * 1024 + d];
      for (int j = 0; j < 1024; ++j) v += xd[j] * Wv[(size_t)j * 4096 + h * 1024 + d];
      z = fmaxf(z, s[h] * v);
    }
    Z[(size_t)i * 1024 + d] = z;
  }
}

extern "C" void kernel_launch(void* const* d_in, const int* in_sizes, int n_in,
                              void* d_out, int out_size, void* d_ws, size_t ws_size,
                              hipStream_t stream) {
  const float* Xd = (const float*)d_in[0];
  const float* Xo = (const float*)d_in[1];
  const float* Wq = (const float*)d_in[2];
  const float* bq = (const float*)d_in[3];
  const float* Wk = (const float*)d_in[4];
  const float* bk = (const float*)d_in[5];
  const float* Wv = (const float*)d_in[6];
  const float* bv = (const float*)d_in[7];
  float* Z = (float*)d_out;
  long N = in_sizes[0] / 1024;

  size_t sz_Xd = (size_t)N * 1024 * 2, sz_Xo = (size_t)N * 512 * 2;
  size_t sz_Wq = (size_t)512 * 512 * 2, sz_Wk = (size_t)512 * 1024 * 2;
  size_t sz_Wv = (size_t)4096 * 1024 * 2;
  size_t sz_Qb = (size_t)N * 512 * 2, sz_sc = (size_t)N * 4 * 4;
  size_t o_Xo = sz_Xd, o_Wq = o_Xo + sz_Xo, o_Wk = o_Wq + sz_Wq,
         o_Wv = o_Wk + sz_Wk, o_Qb = o_Wv + sz_Wv, o_sc = o_Qb + sz_Qb;
  size_t need = o_sc + sz_sc;

  if (ws_size < need || (N % 256) != 0) {
    naive_k<<<(int)N, 256, 0, stream>>>(Xd, Xo, Wq, bq, Wk, bk, Wv, bv, Z);
    return;
  }

  char* w = (char*)d_ws;
  unsigned short* Xd_b = (unsigned short*)w;
  unsigned short* Xo_b = (unsigned short*)(w + o_Xo);
  unsigned short* Wq_t = (unsigned short*)(w + o_Wq);
  unsigned short* Wk_t = (unsigned short*)(w + o_Wk);
  unsigned short* Wv_p = (unsigned short*)(w + o_Wv);
  unsigned short* Qb   = (unsigned short*)(w + o_Qb);
  float* sc = (float*)(w + o_sc);

  conv_k<<<2048, 256, 0, stream>>>(Xd, (short8*)Xd_b, N * 1024 / 8);
  conv_k<<<2048, 256, 0, stream>>>(Xo, (short8*)Xo_b, N * 512 / 8);
  tconv_k<<<dim3(16, 16), 256, 0, stream>>>(Wq, Wq_t, 512, 512, 0);
  tconv_k<<<dim3(32, 16), 256, 0, stream>>>(Wk, Wk_t, 1024, 512, 0);
  tconv_k<<<dim3(32, 128), 256, 0, stream>>>(Wv, Wv_p, 1024, 4096, 1);

  int mt = (int)(N / 256);
  gemm_p<512, 2, 0><<<mt * 2, 512, 0, stream>>>(Xo_b, Wq_t, bq, nullptr, Qb,
                                                nullptr);
  gemm_p<1024, 2, 1><<<mt * 2, 512, 0, stream>>>(Xd_b, Wk_t, bk, Qb, nullptr,
                                                 sc);
  gemm_v32<1024><<<mt * 32, 512, 0, stream>>>(Xd_b, Wv_p, bv, sc, Z);
}

// Round 12
// 460.080 us; speedup vs baseline: 1.4284x; 1.0716x over previous
//
#include <hip/hip_runtime.h>

typedef __attribute__((ext_vector_type(8))) short short8;
typedef __attribute__((ext_vector_type(4))) float f32x4;

// async global->LDS, 16B per lane. LDS dest = wave-uniform base (+ lane*16 by HW).
#define GLL16(gp, lp) __builtin_amdgcn_global_load_lds( \
    (__attribute__((address_space(1))) void*)(gp), \
    (__attribute__((address_space(3))) void*)(lp), 16, 0, 0)

__device__ __forceinline__ unsigned short f2b(float f) {
  unsigned int u = __builtin_bit_cast(unsigned int, f);
  u += 0x7fffu + ((u >> 16) & 1u);   // RNE; inputs are finite
  return (unsigned short)(u >> 16);
}
__device__ __forceinline__ float b2f(unsigned short s) {
  unsigned int u = ((unsigned int)s) << 16;
  return __builtin_bit_cast(float, u);
}

// ---------------- f32 -> bf16 straight convert, Xd and Xo in ONE launch ----------------
__global__ __launch_bounds__(256) void conv2_k(const float* __restrict__ inA,
                                               short8* __restrict__ outA, long nA8,
                                               const float* __restrict__ inB,
                                               short8* __restrict__ outB, long nB8) {
  long tot = nA8 + nB8;
  for (long i = (long)blockIdx.x * 256 + threadIdx.x; i < tot;
       i += (long)gridDim.x * 256) {
    const float4* p;
    short8* o;
    long j;
    if (i < nA8) { j = i; p = (const float4*)inA + 2 * j; o = outA + j; }
    else         { j = i - nA8; p = (const float4*)inB + 2 * j; o = outB + j; }
    float4 a = p[0], b = p[1];
    short8 v;
    v[0] = (short)f2b(a.x); v[1] = (short)f2b(a.y);
    v[2] = (short)f2b(a.z); v[3] = (short)f2b(a.w);
    v[4] = (short)f2b(b.x); v[5] = (short)f2b(b.y);
    v[6] = (short)f2b(b.z); v[7] = (short)f2b(b.w);
    *o = v;
  }
}

// ------------- transpose+convert weights: in (K x C f32) -> out (C x K bf16) -------------
// inter=1 (Wv): output row for input col c = 4*(c&1023) + (c>>10)  (p = 4d+h head-interleave)
__global__ __launch_bounds__(256) void tconv_k(const float* __restrict__ in,
                                               unsigned short* __restrict__ out,
                                               int K, int C, int inter) {
  __shared__ float t[32][33];
  int k0 = blockIdx.x * 32, c0 = blockIdx.y * 32;
  int tx = threadIdx.x & 31, ty = threadIdx.x >> 5;
#pragma unroll
  for (int p = 0; p < 4; ++p)
    t[ty + p * 8][tx] = in[(size_t)(k0 + ty + p * 8) * C + c0 + tx];
  __syncthreads();
#pragma unroll
  for (int p = 0; p < 4; ++p) {
    int c = ty + p * 8;
    int gc = c0 + c;
    int orow = inter ? ((gc & 1023) * 4 + (gc >> 10)) : gc;
    out[(size_t)orow * K + k0 + tx] = f2b(t[tx][c]);
  }
}

// ======== V-GEMM (R9, best-measured 355us): 256x128, BK=32, 8 waves, wave 64x64 ========
// 3-buf ring 24KB, counted vmcnt(3), 1 raw barrier/tile, 2 blocks/CU, ~44% occupancy.
// s_sc prefetch moved AFTER the K-loop (epilogue-only data; frees the fill phase).
// LDS packing (R4/R9-verified): 2 rows per 128B super-row, chunk=(par<<2|kc)^(sr&7).
// Z[row][d] = max_h sc[row][h]*(acc+bv), cols head-interleaved p=4d+h.
template <int KD>
__global__ __launch_bounds__(512, 4) void gemm_v2(
    const unsigned short* __restrict__ A, const unsigned short* __restrict__ Bt,
    const float* __restrict__ bias, const float* __restrict__ sc,
    float* __restrict__ Z) {
  __shared__ __align__(16) char lds[73728];    // 3 bufs x (A 16KB + B 8KB)
  __shared__ float s_sc[1024];

  constexpr int NKT = KD / 32;
  int tid = threadIdx.x;
  int bid = blockIdx.x;
  int cpx = gridDim.x >> 3;                    // grid % 8 == 0 (bijective XCD swizzle)
  int lb = (bid & 7) * cpx + (bid >> 3);
  int mtile = lb >> 5, nt0 = lb & 31;          // 32 ntiles of 128 cols
  long m0 = (long)mtile * 256;
  int l = tid & 63, wid = tid >> 6, wm = wid >> 1, wn = wid & 1;

  // staging source mapping (inverse of read swizzle), R4/R9-verified:
  // dest byte = sr*128 + slot*16 holds global (row = 2*sr+par, kchunk kc),
  // (par<<2|kc) = slot ^ (sr&7).
  int srg = tid >> 3, slot = tid & 7;
  int se = slot ^ (srg & 7);
  int par = se >> 2, kc = se & 3;
  int rowb = srg * 2 + par;                    // row within 128-row group
  const char* aT = (const char*)(A + m0 * KD) + (long)rowb * (KD * 2) + kc * 16;
  const char* bT = (const char*)(Bt + (long)nt0 * 128 * KD) + (long)rowb * (KD * 2) + kc * 16;
  char* ldsb = (char*)lds;
  int dstOff = wid * 1024;                     // wave-uniform dest component

  auto stage = [&](int kt, int bb) {           // one K-tile: A 16KB (2x) + B 8KB (1x)
    int ko = kt * 64;
    GLL16(aT + ko,                  ldsb + bb * 24576 + dstOff);
    GLL16(aT + 128 * (KD * 2) + ko, ldsb + bb * 24576 + 8192 + dstOff);
    GLL16(bT + ko,                  ldsb + bb * 24576 + 16384 + dstOff);
  };

  // read offsets (swizzled), R9-verified
  int ar = l & 15, kcl = l >> 4;
  int aoffR[4], boffR[4];
#pragma unroll
  for (int m = 0; m < 4; ++m) {
    int wr = wm * 64 + m * 16 + ar, sr = wr >> 1;
    aoffR[m] = sr * 128 + (((((wr & 1) << 2) | kcl) ^ (sr & 7)) << 4);
  }
#pragma unroll
  for (int n = 0; n < 4; ++n) {
    int br = wn * 64 + n * 16 + ar, sr = br >> 1;
    boffR[n] = 16384 + sr * 128 + (((((br & 1) << 2) | kcl) ^ (sr & 7)) << 4);
  }

  f32x4 zero = {0.f, 0.f, 0.f, 0.f};
  f32x4 acc[4][4];
#pragma unroll
  for (int m = 0; m < 4; ++m)
#pragma unroll
    for (int n = 0; n < 4; ++n) acc[m][n] = zero;

  stage(0, 0);
  stage(1, 1);                                 // 2-tile prefetch window

  for (int t = 0; t < NKT; ++t) {
    // retire tile t's 3 loads; keep tile t+1's 3 in flight (counted, never drain)
    if (t + 1 < NKT) asm volatile("s_waitcnt vmcnt(3)" ::: "memory");
    else             asm volatile("s_waitcnt vmcnt(0)" ::: "memory");
    __builtin_amdgcn_s_barrier();
    asm volatile("" ::: "memory");
    if (t + 2 < NKT) stage(t + 2, (t + 2) % 3);

    const char* base = ldsb + (t % 3) * 24576;
    short8 af[4], bf[4];
#pragma unroll
    for (int m = 0; m < 4; ++m) af[m] = *(const short8*)(base + aoffR[m]);
#pragma unroll
    for (int n = 0; n < 4; ++n) bf[n] = *(const short8*)(base + boffR[n]);
#pragma unroll
    for (int m = 0; m < 4; ++m)
#pragma unroll
      for (int n = 0; n < 4; ++n)
        acc[m][n] = __builtin_amdgcn_mfma_f32_16x16x32_bf16(af[m], bf[n],
                                                            acc[m][n], 0, 0, 0);
  }

  // s_sc prefetch (epilogue-only data) — after the pipeline, before the drain barrier
  for (int i = tid; i < 1024; i += 512) s_sc[i] = sc[m0 * 4 + i];

  // ---------------- fused epilogue: scale by scores, max over heads ----------------
  __syncthreads();                             // drain before LDS reuse; s_sc visible
  float* Zs = (float*)ldsb;                    // 256 x 32 f32 = 32 KB
#pragma unroll
  for (int n = 0; n < 4; ++n) {
    int pl = wn * 64 + n * 16 + (l & 15);      // local permuted col, p = 4d+h
    int pg = nt0 * 128 + pl;
    int h = pl & 3;
    float bb = bias[(pg & 3) * 1024 + (pg >> 2)];
#pragma unroll
    for (int m = 0; m < 4; ++m) {
      int rl = wm * 64 + m * 16 + ((l >> 4) << 2);
#pragma unroll
      for (int r = 0; r < 4; ++r) {
        float z = s_sc[(rl + r) * 4 + h] * (acc[m][n][r] + bb);
        z = fmaxf(z, __shfl_xor(z, 1));        // max over heads (adjacent p)
        z = fmaxf(z, __shfl_xor(z, 2));
        if ((l & 3) == 0) Zs[(rl + r) * 32 + (pl >> 2)] = z;
      }
    }
  }
  __syncthreads();
#pragma unroll
  for (int it = 0; it < 4; ++it) {             // coalesced float4 stores, 256x32 f32
    int i = it * 512 + tid;
    int row = i >> 3, q = i & 7;
    f32x4 v = *(const f32x4*)&Zs[row * 32 + q * 4];
    *(f32x4*)&Z[(m0 + row) * 1024 + nt0 * 32 + q * 4] = v;
  }
}

// ======== 256x256 BK=64 quadrant-phase GEMM (R7) — Q and K GEMMs ========
template <int KD, int NTI, int EPI>
__global__ __launch_bounds__(512, 2) void gemm_p(
    const unsigned short* __restrict__ A, const unsigned short* __restrict__ Bt,
    const float* __restrict__ bias, const unsigned short* __restrict__ Qb,
    unsigned short* __restrict__ outb, float* __restrict__ sc) {
  __shared__ __align__(16) char lds[131072];   // A slots 0..3 x16KB, B at +64KB

  constexpr int NKT = KD / 64;
  int tid = threadIdx.x;
  int bid = blockIdx.x;
  int cpx = gridDim.x >> 3;
  int lb = (bid & 7) * cpx + (bid >> 3);
  int mtile = lb / NTI, nt0 = lb % NTI;
  long m0 = (long)mtile * 256;
  int l = tid & 63, wid = tid >> 6, wm = wid >> 2, wn = wid & 3;

  int rowg = tid >> 3;
  int swz = (tid & 7) ^ (rowg & 7);
  const char* aSrc = (const char*)(A + m0 * KD) + (long)rowg * (KD * 2) + swz * 16;
  const char* bSrc = (const char*)(Bt + (long)nt0 * 256 * KD) + (long)rowg * (KD * 2) + swz * 16;
  char* ldsb = (char*)lds;
  int dstOff = wid * 1024;

  auto stageA = [&](int hh, int tt) {
    char* base = ldsb + ((tt & 1) * 32768 + hh * 16384) + dstOff;
    const char* s = aSrc + (long)(hh * 128) * (KD * 2) + tt * 128;
    GLL16(s, base);
    GLL16(s + (long)64 * (KD * 2), base + 8192);
  };
  auto stageB = [&](int hh, int tt) {
    char* base = ldsb + 65536 + ((tt & 1) * 32768 + hh * 16384) + dstOff;
    const char* s = bSrc + (long)(hh * 128) * (KD * 2) + tt * 128;
    GLL16(s, base);
    GLL16(s + (long)64 * (KD * 2), base + 8192);
  };

  int ar = l & 15, kcl = l >> 4;
  int x0 = ((kcl ^ (ar & 7)) << 4);
  int x1 = (((4 | kcl) ^ (ar & 7)) << 4);
  int thrA = (wm * 64 + ar) * 128;
  int thrB = (wn * 32 + ar) * 128;

  short8 aA[4][2], aB[4][2], b0[2][2], b1[2][2];

#define RD_A(dst, slotoff)                                                  \
  do {                                                                      \
    const char* p_ = ldsb + (slotoff) + thrA;                               \
    _Pragma("unroll") for (int m_ = 0; m_ < 4; ++m_) {                      \
      dst[m_][0] = *(const short8*)(p_ + x0 + m_ * 2048);                   \
      dst[m_][1] = *(const short8*)(p_ + x1 + m_ * 2048);                   \
    }                                                                       \
  } while (0)
#define RD_B(dst, slotoff)                                                  \
  do {                                                                      \
    const char* p_ = ldsb + 65536 + (slotoff) + thrB;                       \
    _Pragma("unroll") for (int n_ = 0; n_ < 2; ++n_) {                      \
      dst[n_][0] = *(const short8*)(p_ + x0 + n_ * 2048);                   \
      dst[n_][1] = *(const short8*)(p_ + x1 + n_ * 2048);                   \
    }                                                                       \
  } while (0)
#define MFQ(q, am, bn)                                                      \
  do {                                                                      \
    __builtin_amdgcn_s_setprio(1);                                          \
    _Pragma("unroll") for (int m_ = 0; m_ < 4; ++m_)                        \
        _Pragma("unroll") for (int n_ = 0; n_ < 2; ++n_)                    \
            _Pragma("unroll") for (int k_ = 0; k_ < 2; ++k_)                \
                acc[q][m_ * 2 + n_] = __builtin_amdgcn_mfma_f32_16x16x32_bf16( \
                    am[m_][k_], bn[n_][k_], acc[q][m_ * 2 + n_], 0, 0, 0);  \
    __builtin_amdgcn_s_setprio(0);                                          \
  } while (0)
#define VM(n) asm volatile("s_waitcnt vmcnt(" #n ")" ::: "memory")
#define BAR() __builtin_amdgcn_s_barrier()
#define CLOB() asm volatile("" ::: "memory")

  f32x4 zero = {0.f, 0.f, 0.f, 0.f};
  f32x4 acc[4][8];
#pragma unroll
  for (int q = 0; q < 4; ++q)
#pragma unroll
    for (int f = 0; f < 8; ++f) acc[q][f] = zero;

  stageA(0, 0); stageB(0, 0); stageB(1, 0); stageA(1, 0);
  VM(4); BAR(); CLOB();
  RD_A(aA, 0);
  RD_B(b0, 0);

  for (int t = 0; t < NKT - 1; ++t) {
    int aS = (t & 1) * 32768;
    int bS = aS;
    int aS2 = aS ^ 32768;
    stageA(0, t + 1);
    VM(4); BAR(); CLOB();
    RD_B(b1, bS + 16384);
    MFQ(0, aA, b0);
    stageB(0, t + 1);
    VM(4); BAR(); CLOB();
    RD_A(aB, aS + 16384);
    MFQ(1, aA, b1);
    stageB(1, t + 1);
    VM(4); BAR(); CLOB();
    RD_A(aA, aS2);
    MFQ(2, aB, b0);
    stageA(1, t + 1);
    VM(4); BAR(); CLOB();
    RD_B(b0, aS2);
    MFQ(3, aB, b1);
  }
  {
    constexpr int t = NKT - 1;
    int aS = (t & 1) * 32768;
    VM(2); BAR(); CLOB();
    RD_B(b1, aS + 16384);
    MFQ(0, aA, b0);
    VM(0); BAR(); CLOB();
    RD_A(aB, aS + 16384);
    MFQ(1, aA, b1);
    MFQ(2, aB, b0);
    MFQ(3, aB, b1);
  }
#undef RD_A
#undef RD_B
#undef MFQ
#undef VM
#undef BAR
#undef CLOB

  if constexpr (EPI == 0) {
#pragma unroll
    for (int qm = 0; qm < 2; ++qm)
#pragma unroll
      for (int qn = 0; qn < 2; ++qn) {
        int q = qm * 2 + qn;
#pragma unroll
        for (int n = 0; n < 2; ++n) {
          int col = nt0 * 256 + qn * 128 + wn * 32 + n * 16 + (l & 15);
          float bb = bias[col];
#pragma unroll
          for (int m = 0; m < 4; ++m) {
            long rowb = m0 + qm * 128 + wm * 64 + m * 16 + ((l >> 4) << 2);
#pragma unroll
            for (int r = 0; r < 4; ++r)
              outb[(rowb + r) * 512 + col] = f2b(acc[q][m * 2 + n][r] + bb);
          }
        }
      }
  } else {
    float part[2][2][4][4];
#pragma unroll
    for (int qm = 0; qm < 2; ++qm)
#pragma unroll
      for (int qn = 0; qn < 2; ++qn)
#pragma unroll
        for (int m = 0; m < 4; ++m)
#pragma unroll
          for (int r = 0; r < 4; ++r) part[qm][qn][m][r] = 0.f;
#pragma unroll
    for (int qm = 0; qm < 2; ++qm)
#pragma unroll
      for (int qn = 0; qn < 2; ++qn) {
        int q = qm * 2 + qn;
#pragma unroll
        for (int n = 0; n < 2; ++n) {
          int col = nt0 * 256 + qn * 128 + wn * 32 + n * 16 + (l & 15);
          float bb = bias[col];
#pragma unroll
          for (int m = 0; m < 4; ++m) {
            long rowb = m0 + qm * 128 + wm * 64 + m * 16 + ((l >> 4) << 2);
#pragma unroll
            for (int r = 0; r < 4; ++r) {
              float kv = acc[q][m * 2 + n][r] + bb;
              part[qm][qn][m][r] += kv * b2f(Qb[(rowb + r) * 512 + col]);
            }
          }
        }
      }
    __syncthreads();
    float (*sred)[2][4] = (float(*)[2][4])ldsb;   // [256][head2][wn4]
#pragma unroll
    for (int qm = 0; qm < 2; ++qm)
#pragma unroll
      for (int qn = 0; qn < 2; ++qn)
#pragma unroll
        for (int m = 0; m < 4; ++m)
#pragma unroll
          for (int r = 0; r < 4; ++r) {
            float s = part[qm][qn][m][r];
            s += __shfl_xor(s, 1);
            s += __shfl_xor(s, 2);
            s += __shfl_xor(s, 4);
            s += __shfl_xor(s, 8);
            if ((l & 15) == 0)
              sred[qm * 128 + wm * 64 + m * 16 + ((l >> 4) << 2) + r][qn][wn] = s;
          }
    __syncthreads();
    {
      int row = tid >> 1, hh = tid & 1;
      float v = sred[row][hh][0] + sred[row][hh][1] + sred[row][hh][2] +
                sred[row][hh][3];
      sc[(m0 + row) * 4 + nt0 * 2 + hh] = v;
    }
  }
}

// ---------------- fallback (only if ws too small): fp32, correct but slow ----------------
__global__ __launch_bounds__(256) void naive_k(
    const float* __restrict__ Xd, const float* __restrict__ Xo,
    const float* __restrict__ Wq, const float* __restrict__ bq,
    const float* __restrict__ Wk, const float* __restrict__ bk,
    const float* __restrict__ Wv, const float* __restrict__ bv,
    float* __restrict__ Z) {
  int i = blockIdx.x, t = threadIdx.x;
  __shared__ float xd[1024], xo[512], s[4];
  for (int j = t; j < 1024; j += 256) xd[j] = Xd[(size_t)i * 1024 + j];
  for (int j = t; j < 512; j += 256) xo[j] = Xo[(size_t)i * 512 + j];
  if (t < 4) s[t] = 0.f;
  __syncthreads();
  for (int c = t; c < 512; c += 256) {
    float q = bq[c], k = bk[c];
    for (int j = 0; j < 512; ++j) q += xo[j] * Wq[(size_t)j * 512 + c];
    for (int j = 0; j < 1024; ++j) k += xd[j] * Wk[(size_t)j * 512 + c];
    atomicAdd(&s[c >> 7], q * k);
  }
  __syncthreads();
  for (int d = t; d < 1024; d += 256) {
    float z = -INFINITY;
    for (int h = 0; h < 4; ++h) {
      float v = bv[h * 1024 + d];
      for (int j = 0; j < 1024; ++j) v += xd[j] * Wv[(size_t)j * 4096 + h * 1024 + d];
      z = fmaxf(z, s[h] * v);
    }
    Z[(size_t)i * 1024 + d] = z;
  }
}

extern "C" void kernel_launch(void* const* d_in, const int* in_sizes, int n_in,
                              void* d_out, int out_size, void* d_ws, size_t ws_size,
                              hipStream_t stream) {
  const float* Xd = (const float*)d_in[0];
  const float* Xo = (const float*)d_in[1];
  const float* Wq = (const float*)d_in[2];
  const float* bq = (const float*)d_in[3];
  const float* Wk = (const float*)d_in[4];
  const float* bk = (const float*)d_in[5];
  const float* Wv = (const float*)d_in[6];
  const float* bv = (const float*)d_in[7];
  float* Z = (float*)d_out;
  long N = in_sizes[0] / 1024;

  size_t sz_Xd = (size_t)N * 1024 * 2, sz_Xo = (size_t)N * 512 * 2;
  size_t sz_Wq = (size_t)512 * 512 * 2, sz_Wk = (size_t)512 * 1024 * 2;
  size_t sz_Wv = (size_t)4096 * 1024 * 2;
  size_t sz_Qb = (size_t)N * 512 * 2, sz_sc = (size_t)N * 4 * 4;
  size_t o_Xo = sz_Xd, o_Wq = o_Xo + sz_Xo, o_Wk = o_Wq + sz_Wq,
         o_Wv = o_Wk + sz_Wk, o_Qb = o_Wv + sz_Wv, o_sc = o_Qb + sz_Qb;
  size_t need = o_sc + sz_sc;

  if (ws_size < need || (N % 256) != 0) {
    naive_k<<<(int)N, 256, 0, stream>>>(Xd, Xo, Wq, bq, Wk, bk, Wv, bv, Z);
    return;
  }

  char* w = (char*)d_ws;
  unsigned short* Xd_b = (unsigned short*)w;
  unsigned short* Xo_b = (unsigned short*)(w + o_Xo);
  unsigned short* Wq_t = (unsigned short*)(w + o_Wq);
  unsigned short* Wk_t = (unsigned short*)(w + o_Wk);
  unsigned short* Wv_p = (unsigned short*)(w + o_Wv);
  unsigned short* Qb   = (unsigned short*)(w + o_Qb);
  float* sc = (float*)(w + o_sc);

  conv2_k<<<2048, 256, 0, stream>>>(Xd, (short8*)Xd_b, N * 1024 / 8,
                                    Xo, (short8*)Xo_b, N * 512 / 8);
  tconv_k<<<dim3(16, 16), 256, 0, stream>>>(Wq, Wq_t, 512, 512, 0);
  tconv_k<<<dim3(32, 16), 256, 0, stream>>>(Wk, Wk_t, 1024, 512, 0);
  tconv_k<<<dim3(32, 128), 256, 0, stream>>>(Wv, Wv_p, 1024, 4096, 1);

  int mt = (int)(N / 256);
  gemm_p<512, 2, 0><<<mt * 2, 512, 0, stream>>>(Xo_b, Wq_t, bq, nullptr, Qb,
                                                nullptr);
  gemm_p<1024, 2, 1><<<mt * 2, 512, 0, stream>>>(Xd_b, Wk_t, bk, Qb, nullptr,
                                                 sc);
  gemm_v2<1024><<<mt * 32, 512, 0, stream>>>(Xd_b, Wv_p, bv, sc, Z);
}